// Round 21
// baseline (112.392 us; speedup 1.0000x reference)
//
#include <hip/hip_runtime.h>

typedef __attribute__((ext_vector_type(8))) _Float16 half8;
typedef __attribute__((ext_vector_type(4))) float f32x4;

constexpr int NTOK = 65536;
constexpr int DIM  = 128;
constexpr int NK   = 1024;

// ---- prep: emb -> frag-major fp16 image for direct reg loads ----
// frag addr = chunk*8192 + kk*2048 + n*1024 + (lo4*16 + cl)*16
// + embT + f64 |e|^2 + scaled-key e2s; zeroes nflag + icounts.
__global__ void bprep_k(const float* __restrict__ emb, char* __restrict__ bp,
                        float* __restrict__ embT, float* __restrict__ e2s,
                        double* __restrict__ en2d, int* __restrict__ nflag,
                        unsigned* __restrict__ icounts) {
  int i = blockIdx.x * 256 + threadIdx.x;   // 0..16383
  if (i == 0) *nflag = 0;
  if (i < NK) icounts[i] = 0u;
  int c = i >> 4;          // code
  int g = i & 15;          // dim group (8 dims)
  float4 v0 = *(const float4*)&emb[c * 128 + g * 8];
  float4 v1 = *(const float4*)&emb[c * 128 + g * 8 + 4];
  float vf[8] = {v0.x, v0.y, v0.z, v0.w, v1.x, v1.y, v1.z, v1.w};
  half8 hv;
  double pacc = 0.0;
#pragma unroll
  for (int j = 0; j < 8; j++) {
    hv[j] = (_Float16)vf[j];
    embT[(g * 8 + j) * NK + c] = vf[j];
    pacc = fma((double)vf[j], (double)vf[j], pacc);
  }
  int chunk = c >> 5, n = (c >> 4) & 1, cl = c & 15;
  int kk = g >> 2, lo4 = g & 3;
  *(half8*)(bp + chunk * 8192 + kk * 2048 + n * 1024 + (lo4 * 16 + cl) * 16) = hv;
#pragma unroll
  for (int mask = 1; mask < 16; mask <<= 1) pacc += __shfl_xor(pacc, mask);
  if (g == 0) {
    en2d[c] = pacc;
    e2s[c] = (float)(pacc * 134217728.0 + 1073741824.0);  // e2*2^27 + 2^30
  }
}

// ---- main: fp16 MFMA distance + u32-key argmin, m=4, in-block code-split ----
// R19's measured-best config (40.5us): 1024 blocks x 128 thr (2 waves), BM=64,
// both waves cover the same 64 rows, wave w scans code-half w (16 chunks).
// Fused: merge phase bumps icounts atomically (replaces histb_k).
__global__ __launch_bounds__(128, 2)
void argmin_k(const float* __restrict__ x, const char* __restrict__ bp,
              const float* __restrict__ e2s, int* __restrict__ idx_arr,
              float* __restrict__ out_idx, int* __restrict__ nflag,
              int* __restrict__ flags, unsigned* __restrict__ icounts) {
  __shared__ unsigned kvs[2][64], k2s[2][64];
  const int t    = threadIdx.x;
  const int lane = t & 63;
  const int w    = t >> 6;              // 0..1 = code half
  const int l15  = lane & 15;
  const int lo4  = lane >> 4;
  const int rbase = blockIdx.x * 64;
  const int cbase = w * 16;             // first chunk of this wave's half
  const int lb16 = lane * 16;

  half8 FA[4][2], FB[4][2];   // [kk][n]

#define LOADG(DST, C, KK)                                                      \
  {                                                                            \
    const char* _b = bp + ((C) * 8192 + (KK) * 2048) + lb16;                   \
    DST[0] = *(const half8*)_b;                                                \
    DST[1] = *(const half8*)(_b + 1024);                                       \
  }

  // prolog: first two chunks of this half in flight
#pragma unroll
  for (int kk = 0; kk < 4; kk++) LOADG(FA[kk], cbase, kk)
#pragma unroll
  for (int kk = 0; kk < 4; kk++) LOADG(FB[kk], cbase + 1, kk)

  // A-frags (m=4, same 64 rows for both waves): global -> regs, fp16 convert
  half8 ah[4][4];
#pragma unroll
  for (int m = 0; m < 4; m++)
#pragma unroll
    for (int kk = 0; kk < 4; kk++) {
      const float* xp = &x[(rbase + m * 16 + l15) * 128 + kk * 32 + lo4 * 8];
      float4 v0 = *(const float4*)xp;
      float4 v1 = *(const float4*)(xp + 4);
      float vf[8] = {v0.x, v0.y, v0.z, v0.w, v1.x, v1.y, v1.z, v1.w};
      half8 av;
#pragma unroll
      for (int j = 0; j < 8; j++) av[j] = (_Float16)vf[j];
      ah[m][kk] = av;
    }

  unsigned bv[4][4], b2[4][4];
#pragma unroll
  for (int m = 0; m < 4; m++)
#pragma unroll
    for (int r = 0; r < 4; r++) { bv[m][r] = 0xFFFFFFFFu; b2[m][r] = 0xFFFFFFFFu; }

#define MFMA_PHASE(BANK, KK)                                                   \
  {                                                                            \
    _Pragma("unroll")                                                          \
    for (int m = 0; m < 4; m++) {                                              \
      acc[m][0] = __builtin_amdgcn_mfma_f32_16x16x32_f16(ah[m][KK], BANK[KK][0], acc[m][0], 0, 0, 0); \
      acc[m][1] = __builtin_amdgcn_mfma_f32_16x16x32_f16(ah[m][KK], BANK[KK][1], acc[m][1], 0, 0, 0); \
    }                                                                          \
  }

#define KEY_EPI(C)                                                             \
  {                                                                            \
    _Pragma("unroll")                                                          \
    for (int n = 0; n < 2; n++) {                                              \
      unsigned col = (unsigned)((C) * 32 + n * 16 + l15);                      \
      float e2v = n ? e2b : e2a;                                               \
      _Pragma("unroll")                                                        \
      for (int m = 0; m < 4; m++)                                              \
        _Pragma("unroll")                                                      \
        for (int r = 0; r < 4; r++) {                                          \
          float ks = fmaf(acc[m][n][r], -268435456.0f, e2v);                   \
          unsigned key = ((unsigned)ks & 0xFFFFFC00u) | col;                   \
          unsigned old = bv[m][r];                                             \
          bv[m][r] = min(old, key);                                            \
          b2[m][r] = min(b2[m][r], max(old, key));                             \
        }                                                                      \
    }                                                                          \
  }

  for (int i = 0; i < 16; i += 2) {
    const int cg = cbase + i;
    // ---- chunk cg from bank A; refill A with cg+2 (conditional)
    {
      float e2a = e2s[cg * 32 + l15];
      float e2b = e2s[cg * 32 + 16 + l15];
      f32x4 acc[4][2];
#pragma unroll
      for (int m = 0; m < 4; m++)
#pragma unroll
        for (int n = 0; n < 2; n++) acc[m][n] = (f32x4)(0.0f);
#pragma unroll
      for (int kk = 0; kk < 4; kk++) {
        MFMA_PHASE(FA, kk)
        if (i + 2 < 16) LOADG(FA[kk], cg + 2, kk)
      }
      KEY_EPI(cg)
    }
    // ---- chunk cg+1 from bank B; refill B with cg+3
    {
      float e2a = e2s[(cg + 1) * 32 + l15];
      float e2b = e2s[(cg + 1) * 32 + 16 + l15];
      f32x4 acc[4][2];
#pragma unroll
      for (int m = 0; m < 4; m++)
#pragma unroll
        for (int n = 0; n < 2; n++) acc[m][n] = (f32x4)(0.0f);
#pragma unroll
      for (int kk = 0; kk < 4; kk++) {
        MFMA_PHASE(FB, kk)
        if (i + 3 < 16) LOADG(FB[kk], cg + 3, kk)
      }
      KEY_EPI(cg + 1)
    }
  }
#undef LOADG
#undef MFMA_PHASE
#undef KEY_EPI

  // 16-lane reduce per (m,r); stash this wave's per-row keys in LDS
#pragma unroll
  for (int m = 0; m < 4; m++)
#pragma unroll
    for (int r = 0; r < 4; r++) {
      unsigned v = bv[m][r], v2 = b2[m][r];
      for (int mask = 1; mask < 16; mask <<= 1) {
        unsigned ov = __shfl_xor(v, mask);
        unsigned o2 = __shfl_xor(v2, mask);
        v2 = min(min(v2, o2), max(v, ov));
        v  = min(v, ov);
      }
      if (l15 == 0) {
        int lr = m * 16 + lo4 * 4 + r;
        kvs[w][lr] = v;
        k2s[w][lr] = v2;
      }
    }
  __syncthreads();

  // merge halves (threads 0..63), emit idx/flags + atomic histogram
  if (t < 64) {
    unsigned va = kvs[0][t], vb = kvs[1][t];
    unsigned v2 = min(min(k2s[0][t], k2s[1][t]), max(va, vb));
    unsigned v  = min(va, vb);
    int row = rbase + t;
    int ii = (int)(v & 1023u);
    idx_arr[row] = ii;
    out_idx[row] = (float)ii;
    atomicAdd(&icounts[ii], 1u);
    if ((v2 >> 10) - (v >> 10) < 79u) {   // gap < 6e-4 in score units
      int p = atomicAdd(nflag, 1); flags[p] = row;
    }
  }
}

// ---- exact f64 recompute for near-tie rows: 4 rows/batch share embT loads;
//      patches idx + icounts ----
__global__ __launch_bounds__(256)
void fb_k(const float* __restrict__ x, const float* __restrict__ embT,
          const double* __restrict__ en2d, const int* __restrict__ nflag,
          const int* __restrict__ flags, int* __restrict__ idx_arr,
          float* __restrict__ out_idx, unsigned* __restrict__ icounts) {
  int n = *nflag;
  __shared__ double xsh[4][DIM];
  __shared__ double sv[256];
  __shared__ int    si[256];
  int t = threadIdx.x;
  double n0 = en2d[t * 4 + 0], n1 = en2d[t * 4 + 1];
  double n2 = en2d[t * 4 + 2], n3 = en2d[t * 4 + 3];
  for (int base = blockIdx.x * 4; base < n; base += gridDim.x * 4) {
    int nb = min(4, n - base);
    __syncthreads();
    for (int u = t; u < nb * DIM; u += 256) {
      int j = u >> 7, d = u & 127;
      xsh[j][d] = (double)x[flags[base + j] * DIM + d];
    }
    __syncthreads();
    double xe[4][4];
#pragma unroll
    for (int j = 0; j < 4; j++)
#pragma unroll
      for (int q = 0; q < 4; q++) xe[j][q] = 0.0;
    for (int d = 0; d < DIM; d++) {
      float4 v = *(const float4*)&embT[d * NK + t * 4];
      double e0 = (double)v.x, e1 = (double)v.y, e2 = (double)v.z, e3 = (double)v.w;
#pragma unroll
      for (int j = 0; j < 4; j++) {
        double xd = xsh[j][d];
        xe[j][0] = fma(e0, xd, xe[j][0]);
        xe[j][1] = fma(e1, xd, xe[j][1]);
        xe[j][2] = fma(e2, xd, xe[j][2]);
        xe[j][3] = fma(e3, xd, xe[j][3]);
      }
    }
#pragma unroll
    for (int j = 0; j < 4; j++) {
      double s0 = n0 - 2.0 * xe[j][0];
      double s1 = n1 - 2.0 * xe[j][1];
      double s2 = n2 - 2.0 * xe[j][2];
      double s3 = n3 - 2.0 * xe[j][3];
      double bvv = s0; int bii = t * 4;
      if (s1 < bvv) { bvv = s1; bii = t * 4 + 1; }
      if (s2 < bvv) { bvv = s2; bii = t * 4 + 2; }
      if (s3 < bvv) { bvv = s3; bii = t * 4 + 3; }
      sv[t] = bvv; si[t] = bii;
      __syncthreads();
      for (int sh = 128; sh > 0; sh >>= 1) {
        if (t < sh) {
          double ov = sv[t + sh]; int oi = si[t + sh];
          if (ov < sv[t] || (ov == sv[t] && oi < si[t])) { sv[t] = ov; si[t] = oi; }
        }
        __syncthreads();
      }
      if (t == 0 && j < nb) {
        int row = flags[base + j];
        int nw = si[0];
        int old = idx_arr[row];
        if (nw != old) {
          idx_arr[row] = nw;
          out_idx[row] = (float)nw;
          atomicSub(&icounts[old], 1u);
          atomicAdd(&icounts[nw], 1u);
        }
      }
      __syncthreads();
    }
  }
}

// ---- prefix scan of icounts + cursors + ncs/csk (1024 elements only) ----
__global__ void scan_k(const unsigned* __restrict__ icounts, unsigned* __restrict__ offsets,
                       unsigned* __restrict__ cursors, const float* __restrict__ cs,
                       float* __restrict__ out_ncs, float* __restrict__ csk) {
  __shared__ unsigned sc[NK];
  __shared__ float sf[NK];
  int t = threadIdx.x;
  unsigned tot = icounts[t];
  sc[t] = tot;
  __syncthreads();
  for (int off = 1; off < NK; off <<= 1) {
    unsigned v = (t >= off) ? sc[t - off] : 0u;
    __syncthreads();
    sc[t] += v;
    __syncthreads();
  }
  unsigned excl = sc[t] - tot;
  offsets[t] = excl;
  cursors[t] = excl;
  float c0 = cs[t];
  float ncs = c0 * 0.99f + 0.01f * (float)tot;
  out_ncs[t] = ncs;
  sf[t] = c0;
  __syncthreads();
  for (int s = 512; s > 0; s >>= 1) {
    if (t < s) sf[t] += sf[t + s];
    __syncthreads();
  }
  float n = 0.99f * sf[0] + 655.36f;   // sum(ncs) = 0.99*sum(cs) + 0.01*65536
  csk[t] = (ncs + 1e-5f) / (n + 1024.0f * 1e-5f) * n;
}

// ---- scatter row ids (global atomic cursors; 1 row/thread) ----
__global__ __launch_bounds__(1024)
void scatter_k(const int* __restrict__ idx, unsigned* __restrict__ cursors,
               int* __restrict__ order) {
  int r = blockIdx.x * 1024 + threadIdx.x;
  int k = idx[r];
  unsigned p = atomicAdd(&cursors[k], 1u);
  order[p] = r;
}

// ---- fused gather: out_q, loss partials, dw_embed quarter-sums ----
// 4096 blocks = 1024 codes x 4 quarters.
__global__ __launch_bounds__(512)
void fgather_k(const float* __restrict__ x, const float* __restrict__ emb,
               const unsigned* __restrict__ offsets, const unsigned* __restrict__ icounts,
               const int* __restrict__ order, float* __restrict__ out_q,
               float* __restrict__ dwsum4, float* __restrict__ partial4) {
  __shared__ int ids[1024];
  int k = blockIdx.x >> 2, q = blockIdx.x & 3;
  int t = threadIdx.x;
  int d = t & 127, h = t >> 7;   // h = 0..3
  unsigned cnt = icounts[k];
  unsigned qs = (cnt * (unsigned)q) >> 2;
  unsigned qe = (cnt * (unsigned)(q + 1)) >> 2;
  unsigned s = offsets[k] + qs;
  unsigned myc = qe - qs;
  for (unsigned j = t; j < myc && j < 1024u; j += 512) ids[j] = order[s + j];
  __syncthreads();
  float e = emb[k * DIM + d];
  float acc = 0.f, ls = 0.f;
#pragma unroll 2
  for (unsigned j = h; j < myc; j += 4) {
    int row = (j < 1024u) ? ids[j] : order[s + j];
    float xv = x[row * DIM + d];
    out_q[row * DIM + d] = e;
    acc += xv;
    float dd = e - xv;
    ls += dd * dd;
  }
  __shared__ float sa[512], sl[512];
  sa[t] = acc; sl[t] = ls;
  __syncthreads();
  if (t < 128) dwsum4[(q * NK + k) * DIM + t] = sa[t] + sa[t + 128] + sa[t + 256] + sa[t + 384];
  for (int sh = 256; sh > 0; sh >>= 1) {
    if (t < sh) sl[t] += sl[t + sh];
    __syncthreads();
  }
  if (t == 0) partial4[blockIdx.x] = sl[0];
}

// ---- embed_avg EMA + new embedding; block 0 reduces loss ----
__global__ void emb_k(const float* __restrict__ embed_avg, const float* __restrict__ dwsum4,
                      const float* __restrict__ csk, const float* __restrict__ partial4,
                      float* __restrict__ out_nemb, float* __restrict__ out_nea,
                      float* __restrict__ out_loss) {
  if (blockIdx.x == 0) {
    __shared__ float red[256];
    int t = threadIdx.x;
    float v = 0.f;
#pragma unroll
    for (int i = 0; i < 16; i++) v += partial4[t + 256 * i];
    red[t] = v;
    __syncthreads();
    for (int sh = 128; sh > 0; sh >>= 1) {
      if (t < sh) red[t] += red[t + sh];
      __syncthreads();
    }
    if (t == 0) out_loss[0] = 2.0f * red[0] / 8388608.0f;
    return;
  }
  int i = (blockIdx.x - 1) * 256 + threadIdx.x;
  float dw = dwsum4[i] + dwsum4[NK * DIM + i] + dwsum4[2 * NK * DIM + i] + dwsum4[3 * NK * DIM + i];
  float na = embed_avg[i] * 0.99f + 0.01f * dw;
  out_nea[i] = na;
  out_nemb[i] = na / csk[i >> 7];
}

extern "C" void kernel_launch(void* const* d_in, const int* in_sizes, int n_in,
                              void* d_out, int out_size, void* d_ws, size_t ws_size,
                              hipStream_t stream) {
  const float* x   = (const float*)d_in[0];
  const float* emb = (const float*)d_in[1];
  const float* cs  = (const float*)d_in[2];
  const float* ea  = (const float*)d_in[3];

  float* out      = (float*)d_out;
  float* out_q    = out;                      // [65536,128]
  float* out_loss = out + 8388608;            // scalar
  float* out_idx  = out + 8388609;            // [65536]
  float* out_nemb = out + 8454145;            // [1024,128]
  float* out_ncs  = out + 8585217;            // [1024]
  float* out_nea  = out + 8586241;            // [1024,128]

  float* W        = (float*)d_ws;
  float* e2s      = W;                              // [0,1024)
  double* en2d    = (double*)(W + 1024);            // [1024,3072)
  char*  bpack    = (char*)(W + 3072);              // 256KB fp16 image (+pad)
  float* embT     = W + 72704;                      // [72704,203776)
  unsigned* icounts = (unsigned*)(W + 203776);      // 1024
  unsigned* offsets = (unsigned*)(W + 204800);      // 1024
  unsigned* cursors = (unsigned*)(W + 205824);      // 1024
  float* csk      = W + 206848;                     // 1024
  int*   nflag    = (int*)(W + 207872);             // 1 (+pad)
  int*   flags    = (int*)(W + 207888);             // 65536
  int*   idx_arr  = (int*)(W + 273424);             // 65536
  int*   order    = (int*)(W + 338960);             // 65536
  float* dwsum4   = W + 404496;                     // 4*1024*128 = 524288
  float* partial4 = W + 928784;                     // 4096

  bprep_k<<<64, 256, 0, stream>>>(emb, bpack, embT, e2s, en2d, nflag, icounts);
  argmin_k<<<1024, 128, 0, stream>>>(x, bpack, e2s, idx_arr, out_idx, nflag, flags, icounts);
  fb_k<<<256, 256, 0, stream>>>(x, embT, en2d, nflag, flags, idx_arr, out_idx, icounts);
  scan_k<<<1, 1024, 0, stream>>>(icounts, offsets, cursors, cs, out_ncs, csk);
  scatter_k<<<64, 1024, 0, stream>>>(idx_arr, cursors, order);
  fgather_k<<<4096, 512, 0, stream>>>(x, emb, offsets, icounts, order, out_q, dwsum4, partial4);
  emb_k<<<513, 256, 0, stream>>>(ea, dwsum4, csk, partial4, out_nemb, out_nea, out_loss);
}

// Round 22
// 97.194 us; speedup vs baseline: 1.1564x; 1.1564x over previous
//
#include <hip/hip_runtime.h>

typedef __attribute__((ext_vector_type(8))) _Float16 half8;
typedef __attribute__((ext_vector_type(4))) float f32x4;

constexpr int NTOK = 65536;
constexpr int DIM  = 128;
constexpr int NK   = 1024;

// ---- prep: emb -> frag-major fp16 image for direct reg loads ----
// frag addr = chunk*8192 + kk*2048 + n*1024 + (lo4*16 + cl)*16
// + embT + f64 |e|^2 + scaled-key e2s; zeroes nflag.
__global__ void bprep_k(const float* __restrict__ emb, char* __restrict__ bp,
                        float* __restrict__ embT, float* __restrict__ e2s,
                        double* __restrict__ en2d, int* __restrict__ nflag) {
  int i = blockIdx.x * 256 + threadIdx.x;   // 0..16383
  if (i == 0) *nflag = 0;
  int c = i >> 4;          // code
  int g = i & 15;          // dim group (8 dims)
  float4 v0 = *(const float4*)&emb[c * 128 + g * 8];
  float4 v1 = *(const float4*)&emb[c * 128 + g * 8 + 4];
  float vf[8] = {v0.x, v0.y, v0.z, v0.w, v1.x, v1.y, v1.z, v1.w};
  half8 hv;
  double pacc = 0.0;
#pragma unroll
  for (int j = 0; j < 8; j++) {
    hv[j] = (_Float16)vf[j];
    embT[(g * 8 + j) * NK + c] = vf[j];
    pacc = fma((double)vf[j], (double)vf[j], pacc);
  }
  int chunk = c >> 5, n = (c >> 4) & 1, cl = c & 15;
  int kk = g >> 2, lo4 = g & 3;
  *(half8*)(bp + chunk * 8192 + kk * 2048 + n * 1024 + (lo4 * 16 + cl) * 16) = hv;
#pragma unroll
  for (int mask = 1; mask < 16; mask <<= 1) pacc += __shfl_xor(pacc, mask);
  if (g == 0) {
    en2d[c] = pacc;
    e2s[c] = (float)(pacc * 134217728.0 + 1073741824.0);  // e2*2^27 + 2^30
  }
}

// ---- main: fp16 MFMA distance + u32-key argmin ----
// 1024 blocks x 128 thr (2 waves). No LDS, no barriers: B-frags streamed
// global(L2)->reg via dual 4x2 register banks (2-chunk / 8-phase lookahead).
__global__ __launch_bounds__(128, 2)
void argmin_k(const float* __restrict__ x, const char* __restrict__ bp,
              const float* __restrict__ e2s, int* __restrict__ idx_arr,
              float* __restrict__ out_idx, int* __restrict__ nflag,
              int* __restrict__ flags) {
  const int t    = threadIdx.x;
  const int lane = t & 63;
  const int w    = t >> 6;              // 0..1
  const int l15  = lane & 15;
  const int lo4  = lane >> 4;
  const int rbase = blockIdx.x * 64;
  const int lb16 = lane * 16;

  half8 FA[4][2], FB[4][2];   // [kk][n]

#define LOADG(DST, C, KK)                                                      \
  {                                                                            \
    const char* _b = bp + ((C) * 8192 + (KK) * 2048) + lb16;                   \
    DST[0] = *(const half8*)_b;                                                \
    DST[1] = *(const half8*)(_b + 1024);                                       \
  }

  // prolog: chunks 0 and 1 fully in flight
#pragma unroll
  for (int kk = 0; kk < 4; kk++) LOADG(FA[kk], 0, kk)
#pragma unroll
  for (int kk = 0; kk < 4; kk++) LOADG(FB[kk], 1, kk)

  // A-frags (m=2): global -> regs, fp16 convert
  half8 ah[2][4];
#pragma unroll
  for (int m = 0; m < 2; m++)
#pragma unroll
    for (int kk = 0; kk < 4; kk++) {
      const float* xp = &x[(rbase + w * 32 + m * 16 + l15) * 128 + kk * 32 + lo4 * 8];
      float4 v0 = *(const float4*)xp;
      float4 v1 = *(const float4*)(xp + 4);
      float vf[8] = {v0.x, v0.y, v0.z, v0.w, v1.x, v1.y, v1.z, v1.w};
      half8 av;
#pragma unroll
      for (int j = 0; j < 8; j++) av[j] = (_Float16)vf[j];
      ah[m][kk] = av;
    }

  unsigned bv[2][4], b2[2][4];
#pragma unroll
  for (int m = 0; m < 2; m++)
#pragma unroll
    for (int r = 0; r < 4; r++) { bv[m][r] = 0xFFFFFFFFu; b2[m][r] = 0xFFFFFFFFu; }

#define MFMA_PHASE(BANK, KK)                                                   \
  {                                                                            \
    acc[0][0] = __builtin_amdgcn_mfma_f32_16x16x32_f16(ah[0][KK], BANK[KK][0], acc[0][0], 0, 0, 0); \
    acc[1][0] = __builtin_amdgcn_mfma_f32_16x16x32_f16(ah[1][KK], BANK[KK][0], acc[1][0], 0, 0, 0); \
    acc[0][1] = __builtin_amdgcn_mfma_f32_16x16x32_f16(ah[0][KK], BANK[KK][1], acc[0][1], 0, 0, 0); \
    acc[1][1] = __builtin_amdgcn_mfma_f32_16x16x32_f16(ah[1][KK], BANK[KK][1], acc[1][1], 0, 0, 0); \
  }

#define KEY_EPI(C)                                                             \
  {                                                                            \
    _Pragma("unroll")                                                          \
    for (int n = 0; n < 2; n++) {                                              \
      unsigned col = (unsigned)((C) * 32 + n * 16 + l15);                      \
      float e2v = n ? e2b : e2a;                                               \
      _Pragma("unroll")                                                        \
      for (int m = 0; m < 2; m++)                                              \
        _Pragma("unroll")                                                      \
        for (int r = 0; r < 4; r++) {                                          \
          float ks = fmaf(acc[m][n][r], -268435456.0f, e2v);                   \
          unsigned key = ((unsigned)ks & 0xFFFFFC00u) | col;                   \
          unsigned old = bv[m][r];                                             \
          bv[m][r] = min(old, key);                                            \
          b2[m][r] = min(b2[m][r], max(old, key));                             \
        }                                                                      \
    }                                                                          \
  }

  for (int c = 0; c < 32; c += 2) {
    {
      float e2a = e2s[c * 32 + l15];
      float e2b = e2s[c * 32 + 16 + l15];
      f32x4 acc[2][2];
#pragma unroll
      for (int m = 0; m < 2; m++)
#pragma unroll
        for (int n = 0; n < 2; n++) acc[m][n] = (f32x4)(0.0f);
#pragma unroll
      for (int kk = 0; kk < 4; kk++) {
        MFMA_PHASE(FA, kk)
        if (c + 2 < 32) LOADG(FA[kk], c + 2, kk)
      }
      KEY_EPI(c)
    }
    {
      float e2a = e2s[(c + 1) * 32 + l15];
      float e2b = e2s[(c + 1) * 32 + 16 + l15];
      f32x4 acc[2][2];
#pragma unroll
      for (int m = 0; m < 2; m++)
#pragma unroll
        for (int n = 0; n < 2; n++) acc[m][n] = (f32x4)(0.0f);
#pragma unroll
      for (int kk = 0; kk < 4; kk++) {
        MFMA_PHASE(FB, kk)
        if (c + 3 < 32) LOADG(FB[kk], c + 3, kk)
      }
      KEY_EPI(c + 1)
    }
  }
#undef LOADG
#undef MFMA_PHASE
#undef KEY_EPI

  // reduce over the 16 column-lanes (u32 min keeps tie-break = smaller col)
#pragma unroll
  for (int m = 0; m < 2; m++)
#pragma unroll
    for (int r = 0; r < 4; r++) {
      unsigned v = bv[m][r], v2 = b2[m][r];
      for (int mask = 1; mask < 16; mask <<= 1) {
        unsigned ov = __shfl_xor(v, mask);
        unsigned o2 = __shfl_xor(v2, mask);
        v2 = min(min(v2, o2), max(v, ov));
        v  = min(v, ov);
      }
      if (l15 == 0) {
        int row = rbase + w * 32 + m * 16 + lo4 * 4 + r;
        int ii = (int)(v & 1023u);
        idx_arr[row] = ii;
        out_idx[row] = (float)ii;
        if ((v2 >> 10) - (v >> 10) < 79u) {   // gap < 6e-4 in score units
          int p = atomicAdd(nflag, 1); flags[p] = row;
        }
      }
    }
}

// ---- exact f64 recompute for near-tie rows (coalesced via embT) ----
__global__ __launch_bounds__(256)
void fb_k(const float* __restrict__ x, const float* __restrict__ embT,
          const double* __restrict__ en2d, const int* __restrict__ nflag,
          const int* __restrict__ flags, int* __restrict__ idx_arr,
          float* __restrict__ out_idx) {
  int n = *nflag;
  __shared__ double xsh[DIM];
  __shared__ double sv[256];
  __shared__ int    si[256];
  int t = threadIdx.x;
  for (int f = blockIdx.x; f < n; f += gridDim.x) {
    int row = flags[f];
    __syncthreads();
    if (t < DIM) xsh[t] = (double)x[row * DIM + t];
    __syncthreads();
    double xe0 = 0.0, xe1 = 0.0, xe2 = 0.0, xe3 = 0.0;
#pragma unroll 4
    for (int d = 0; d < DIM; d++) {
      float4 v = *(const float4*)&embT[d * NK + t * 4];
      double xd = xsh[d];
      xe0 = fma((double)v.x, xd, xe0);
      xe1 = fma((double)v.y, xd, xe1);
      xe2 = fma((double)v.z, xd, xe2);
      xe3 = fma((double)v.w, xd, xe3);
    }
    double s0 = en2d[t * 4 + 0] - 2.0 * xe0;
    double s1 = en2d[t * 4 + 1] - 2.0 * xe1;
    double s2 = en2d[t * 4 + 2] - 2.0 * xe2;
    double s3 = en2d[t * 4 + 3] - 2.0 * xe3;
    double bvv = s0; int bii = t * 4;
    if (s1 < bvv) { bvv = s1; bii = t * 4 + 1; }
    if (s2 < bvv) { bvv = s2; bii = t * 4 + 2; }
    if (s3 < bvv) { bvv = s3; bii = t * 4 + 3; }
    sv[t] = bvv; si[t] = bii;
    __syncthreads();
    for (int sh = 128; sh > 0; sh >>= 1) {
      if (t < sh) {
        double ov = sv[t + sh]; int oi = si[t + sh];
        if (ov < sv[t] || (ov == sv[t] && oi < si[t])) { sv[t] = ov; si[t] = oi; }
      }
      __syncthreads();
    }
    if (t == 0) { idx_arr[row] = si[0]; out_idx[row] = (float)si[0]; }
  }
}

// ---- per-block histogram (LDS bins, plain stores) ----
__global__ void histb_k(const int* __restrict__ idx, unsigned* __restrict__ bcount) {
  __shared__ unsigned bins[NK];
  int t = threadIdx.x;
  for (int b = t; b < NK; b += 256) bins[b] = 0u;
  __syncthreads();
#pragma unroll
  for (int j = 0; j < 4; j++)
    atomicAdd(&bins[idx[blockIdx.x * 1024 + j * 256 + t]], 1u);
  __syncthreads();
  for (int b = t; b < NK; b += 256) bcount[blockIdx.x * NK + b] = bins[b];
}

// ---- totals + scan + per-block starts + ncs/csk ----
__global__ void scan_k(unsigned* __restrict__ bcount, unsigned* __restrict__ icounts,
                       unsigned* __restrict__ offsets, const float* __restrict__ cs,
                       float* __restrict__ out_ncs, float* __restrict__ csk) {
  __shared__ unsigned sc[NK];
  __shared__ float sf[NK];
  int t = threadIdx.x;
  unsigned tot = 0;
#pragma unroll 8
  for (int b = 0; b < 64; b++) tot += bcount[b * NK + t];
  icounts[t] = tot;
  sc[t] = tot;
  __syncthreads();
  for (int off = 1; off < NK; off <<= 1) {
    unsigned v = (t >= off) ? sc[t - off] : 0u;
    __syncthreads();
    sc[t] += v;
    __syncthreads();
  }
  unsigned excl = sc[t] - tot;
  offsets[t] = excl;
  unsigned run = excl;
#pragma unroll 8
  for (int b = 0; b < 64; b++) {
    unsigned c = bcount[b * NK + t];
    bcount[b * NK + t] = run;          // becomes per-block start
    run += c;
  }
  float c0 = cs[t];
  float ncs = c0 * 0.99f + 0.01f * (float)tot;
  out_ncs[t] = ncs;
  sf[t] = c0;
  __syncthreads();
  for (int s = 512; s > 0; s >>= 1) {
    if (t < s) sf[t] += sf[t + s];
    __syncthreads();
  }
  float n = 0.99f * sf[0] + 655.36f;   // sum(ncs) = 0.99*sum(cs) + 0.01*65536
  csk[t] = (ncs + 1e-5f) / (n + 1024.0f * 1e-5f) * n;
}

// ---- scatter row ids (LDS cursors; no global atomics) ----
__global__ void scatter_k(const int* __restrict__ idx, const unsigned* __restrict__ bstart,
                          int* __restrict__ order) {
  __shared__ unsigned cur[NK];
  int t = threadIdx.x;
  for (int b = t; b < NK; b += 256) cur[b] = bstart[blockIdx.x * NK + b];
  __syncthreads();
#pragma unroll
  for (int j = 0; j < 4; j++) {
    int r = blockIdx.x * 1024 + j * 256 + t;
    unsigned p = atomicAdd(&cur[idx[r]], 1u);
    order[p] = r;
  }
}

// ---- fused gather: out_q, loss partials, dw_embed half-sums ----
// 2048 blocks = 1024 codes x 2 halves; order-slice staged in LDS, unrolled loop.
__global__ __launch_bounds__(512)
void fgather_k(const float* __restrict__ x, const float* __restrict__ emb,
               const unsigned* __restrict__ offsets, const unsigned* __restrict__ icounts,
               const int* __restrict__ order, float* __restrict__ out_q,
               float* __restrict__ dwsum2, float* __restrict__ partial2) {
  __shared__ int ids[1024];
  int k = blockIdx.x >> 1, half = blockIdx.x & 1;
  int t = threadIdx.x;
  int d = t & 127, h = t >> 7;   // h = 0..3
  unsigned cnt = icounts[k];
  unsigned chl = cnt >> 1;
  unsigned s = offsets[k] + (half ? chl : 0u);
  unsigned myc = half ? (cnt - chl) : chl;
  for (unsigned j = t; j < myc && j < 1024u; j += 512) ids[j] = order[s + j];
  __syncthreads();
  float e = emb[k * DIM + d];
  float acc = 0.f, ls = 0.f;
#pragma unroll 4
  for (unsigned j = h; j < myc; j += 4) {
    int row = (j < 1024u) ? ids[j] : order[s + j];
    float xv = x[row * DIM + d];
    out_q[row * DIM + d] = e;
    acc += xv;
    float dd = e - xv;
    ls += dd * dd;
  }
  __shared__ float sa[512], sl[512];
  sa[t] = acc; sl[t] = ls;
  __syncthreads();
  if (t < 128) dwsum2[(half * NK + k) * DIM + t] = sa[t] + sa[t + 128] + sa[t + 256] + sa[t + 384];
  for (int sh = 256; sh > 0; sh >>= 1) {
    if (t < sh) sl[t] += sl[t + sh];
    __syncthreads();
  }
  if (t == 0) partial2[blockIdx.x] = sl[0];
}

// ---- embed_avg EMA + new embedding; block 0 reduces loss ----
__global__ void emb_k(const float* __restrict__ embed_avg, const float* __restrict__ dwsum2,
                      const float* __restrict__ csk, const float* __restrict__ partial2,
                      float* __restrict__ out_nemb, float* __restrict__ out_nea,
                      float* __restrict__ out_loss) {
  if (blockIdx.x == 0) {
    __shared__ float red[256];
    int t = threadIdx.x;
    float v = 0.f;
#pragma unroll
    for (int i = 0; i < 8; i++) v += partial2[t + 256 * i];
    red[t] = v;
    __syncthreads();
    for (int sh = 128; sh > 0; sh >>= 1) {
      if (t < sh) red[t] += red[t + sh];
      __syncthreads();
    }
    if (t == 0) out_loss[0] = 2.0f * red[0] / 8388608.0f;
    return;
  }
  int i = (blockIdx.x - 1) * 256 + threadIdx.x;
  float dw = dwsum2[i] + dwsum2[NK * DIM + i];
  float na = embed_avg[i] * 0.99f + 0.01f * dw;
  out_nea[i] = na;
  out_nemb[i] = na / csk[i >> 7];
}

extern "C" void kernel_launch(void* const* d_in, const int* in_sizes, int n_in,
                              void* d_out, int out_size, void* d_ws, size_t ws_size,
                              hipStream_t stream) {
  const float* x   = (const float*)d_in[0];
  const float* emb = (const float*)d_in[1];
  const float* cs  = (const float*)d_in[2];
  const float* ea  = (const float*)d_in[3];

  float* out      = (float*)d_out;
  float* out_q    = out;                      // [65536,128]
  float* out_loss = out + 8388608;            // scalar
  float* out_idx  = out + 8388609;            // [65536]
  float* out_nemb = out + 8454145;            // [1024,128]
  float* out_ncs  = out + 8585217;            // [1024]
  float* out_nea  = out + 8586241;            // [1024,128]

  float* W        = (float*)d_ws;
  float* e2s      = W;                              // [0,1024)
  double* en2d    = (double*)(W + 1024);            // [1024,3072)
  char*  bpack    = (char*)(W + 3072);              // 256KB fp16 image
  float* embT     = W + 134144;                     // [134144,265216) (dead after fb)
  unsigned* bcount = (unsigned*)(W + 134144);       // aliases embT lower (after fb)
  int*   order    = (int*)(W + 199680);             // aliases embT upper (after fb)
  unsigned* icounts = (unsigned*)(W + 266240);      // 1024
  unsigned* offsets = (unsigned*)(W + 267264);      // 1024
  float* csk      = W + 268288;                     // 1024
  int*   nflag    = (int*)(W + 269312);             // 1 (+pad)
  int*   flags    = (int*)(W + 269328);             // 65536
  int*   idx_arr  = (int*)(W + 334864);             // 65536
  float* dwsum2   = W + 400400;                     // 2*1024*128 = 262144
  float* partial2 = W + 662544;                     // 2048

  bprep_k<<<64, 256, 0, stream>>>(emb, bpack, embT, e2s, en2d, nflag);
  argmin_k<<<1024, 128, 0, stream>>>(x, bpack, e2s, idx_arr, out_idx, nflag, flags);
  fb_k<<<1024, 256, 0, stream>>>(x, embT, en2d, nflag, flags, idx_arr, out_idx);
  histb_k<<<64, 256, 0, stream>>>(idx_arr, bcount);
  scan_k<<<1, 1024, 0, stream>>>(bcount, icounts, offsets, cs, out_ncs, csk);
  scatter_k<<<64, 256, 0, stream>>>(idx_arr, bcount, order);
  fgather_k<<<2048, 512, 0, stream>>>(x, emb, offsets, icounts, order, out_q, dwsum2, partial2);
  emb_k<<<513, 256, 0, stream>>>(ea, dwsum2, csk, partial2, out_nemb, out_nea, out_loss);
}